// Round 9
// baseline (1996.261 us; speedup 1.0000x reference)
//
#include <hip/hip_runtime.h>

typedef unsigned short u16;
typedef unsigned int   u32;
typedef u16   u16x8 __attribute__((ext_vector_type(8)));
typedef __bf16 bf16x8 __attribute__((ext_vector_type(8)));
typedef float f32x4 __attribute__((ext_vector_type(4)));
typedef float f32x4v __attribute__((ext_vector_type(4)));

#define N_NODES 4096
#define N_EDGES 16384
#define N_EFEAT 16384
#define SEQ 8
#define DIM 512
#define NLAYER 2
#define NROWS_X (N_NODES*SEQ)     /* 32768 */
#define NROWS_E (N_EDGES*SEQ)     /* 131072 */

__device__ __forceinline__ float b2f(u16 u){ return __uint_as_float(((u32)u)<<16); }
__device__ __forceinline__ u16 f2b(float f){ u32 b=__float_as_uint(f); b += 0x7FFFu + ((b>>16)&1u); return (u16)(b>>16); }

__device__ __forceinline__ void gl16(const u16* g, u16* l) {
    __builtin_amdgcn_global_load_lds((const __attribute__((address_space(1))) void*)g,
                                     (__attribute__((address_space(3))) void*)l, 16, 0, 0);
}

// ---------------- weight transpose + norm-w fold: dst[N][K] = src[K][N] * fold[K] ----------------
__global__ void k_tf(const float* __restrict__ src, u16* __restrict__ dst,
                     const float* __restrict__ fold, int K, int N)
{
    int idx = blockIdx.x * 256 + threadIdx.x;
    if (idx >= K * N) return;
    int c = idx / N, j = idx - c * N;
    float v = src[idx];
    if (fold) v *= fold[c];
    dst[(size_t)j * K + c] = f2b(v);
}

// ---------------- per-row: sumsq -> scale, write raw bf16 copy (wave per row) ----------------
__global__ void k_rowprep(const float* __restrict__ src, u16* __restrict__ dst,
                          float* __restrict__ scale)
{
    int row  = blockIdx.x * 4 + (threadIdx.x >> 6);
    int lane = threadIdx.x & 63;
    const float* p = src + (size_t)row * DIM;
    f32x4v v0 = *(const f32x4v*)(p + lane * 8);
    f32x4v v1 = *(const f32x4v*)(p + lane * 8 + 4);
    float ss = v0[0]*v0[0]+v0[1]*v0[1]+v0[2]*v0[2]+v0[3]*v0[3]
             + v1[0]*v1[0]+v1[1]*v1[1]+v1[2]*v1[2]+v1[3]*v1[3];
    #pragma unroll
    for (int d = 1; d < 64; d <<= 1) ss += __shfl_xor(ss, d);
    if (lane == 0) scale[row] = rsqrtf(ss / (float)DIM + 1e-6f);
    u16x8 o;
    #pragma unroll
    for (int i = 0; i < 4; ++i) o[i] = f2b(v0[i]);
    #pragma unroll
    for (int i = 0; i < 4; ++i) o[4+i] = f2b(v1[i]);
    *(u16x8*)(dst + (size_t)row * DIM + lane * 8) = o;
}

// ---------------- feature dedup: ekv[e] = (RMS(feat) @ We)[emap[e]] (RMS commutes w/ gather) --
__global__ void k_mark(const int* __restrict__ emap, int* __restrict__ flag)
{
    int e = blockIdx.x * 256 + threadIdx.x;
    if (e < N_EDGES) flag[emap[e]] = 1;
}
// single block: exclusive scan of flag[16384] -> newid; ulist[newid[m]] = m; ucnt = total
__global__ void k_scanf(const int* __restrict__ flag, int* __restrict__ newid,
                        int* __restrict__ ulist, int* __restrict__ ucnt)
{
    __shared__ int part[256];
    int t = threadIdx.x;
    int base = t * 64;
    int loc[64]; int s = 0;
    #pragma unroll
    for (int i = 0; i < 64; ++i) { loc[i] = s; s += flag[base + i]; }
    part[t] = s; __syncthreads();
    for (int d = 1; d < 256; d <<= 1) {
        int v = (t >= d) ? part[t - d] : 0;
        __syncthreads();
        part[t] += v;
        __syncthreads();
    }
    int pre = (t == 0) ? 0 : part[t - 1];
    #pragma unroll
    for (int i = 0; i < 64; ++i) {
        int m = base + i;
        int id = pre + loc[i];
        newid[m] = id;
        if (flag[m]) ulist[id] = m;
    }
    if (t == 255) ucnt[0] = part[255];
}
__global__ void k_fidx(const int* __restrict__ emap, const int* __restrict__ newid,
                       int* __restrict__ fidx)
{
    int e = blockIdx.x * 256 + threadIdx.x;
    if (e < N_EDGES) fidx[e] = newid[emap[e]];
}
// compact-feature rows: RMS scale + bf16 copy (wave per row); rows >= ucnt*8 skipped
__global__ void k_featprep(const float* __restrict__ hidden, const int* __restrict__ ulist,
                           const int* __restrict__ ucnt,
                           u16* __restrict__ fbf, float* __restrict__ scale)
{
    int fr = blockIdx.x * 4 + (threadIdx.x >> 6);   // compact row = j*8+l
    if (fr >= ucnt[0] * SEQ) return;
    int lane = threadIdx.x & 63;
    int j = fr >> 3, l = fr & 7;
    const float* p = hidden + ((size_t)(N_NODES + ulist[j]) * SEQ + l) * DIM;
    f32x4v v0 = *(const f32x4v*)(p + lane * 8);
    f32x4v v1 = *(const f32x4v*)(p + lane * 8 + 4);
    float ss = v0[0]*v0[0]+v0[1]*v0[1]+v0[2]*v0[2]+v0[3]*v0[3]
             + v1[0]*v1[0]+v1[1]*v1[1]+v1[2]*v1[2]+v1[3]*v1[3];
    #pragma unroll
    for (int d = 1; d < 64; d <<= 1) ss += __shfl_xor(ss, d);
    if (lane == 0) scale[fr] = rsqrtf(ss / (float)DIM + 1e-6f);
    u16x8 o;
    #pragma unroll
    for (int i = 0; i < 4; ++i) o[i] = f2b(v0[i]);
    #pragma unroll
    for (int i = 0; i < 4; ++i) o[4+i] = f2b(v1[i]);
    *(u16x8*)(fbf + (size_t)fr * DIM + lane * 8) = o;
}

// ---------------- CSR build ----------------
__global__ void k_count(const int* __restrict__ dstA, int* __restrict__ cnt)
{
    int e = blockIdx.x * 256 + threadIdx.x;
    if (e < N_EDGES) atomicAdd(&cnt[dstA[e]], 1);
}
__global__ void k_scan(const int* __restrict__ cnt, int* __restrict__ off)
{
    __shared__ int part[256];
    int t = threadIdx.x;
    int base = t * 16;
    int loc[16]; int s = 0;
    #pragma unroll
    for (int i = 0; i < 16; ++i) { loc[i] = s; s += cnt[base + i]; }
    part[t] = s; __syncthreads();
    for (int d = 1; d < 256; d <<= 1) {
        int v = (t >= d) ? part[t - d] : 0;
        __syncthreads();
        part[t] += v;
        __syncthreads();
    }
    int pre = (t == 0) ? 0 : part[t - 1];
    #pragma unroll
    for (int i = 0; i < 16; ++i) off[base + i] = pre + loc[i];
    if (t == 255) off[N_NODES] = part[255];
}
__global__ void k_fill(const int* __restrict__ dstA, const int* __restrict__ off,
                       int* __restrict__ cur, int* __restrict__ elist)
{
    int e = blockIdx.x * 256 + threadIdx.x;
    if (e < N_EDGES) {
        int d = dstA[e];
        int pos = off[d] + atomicAdd(&cur[d], 1);
        elist[pos] = e;
    }
}

// ---------------- bf16 MFMA GEMM: 128x128 tile, BK=32, 4 waves of 64x64 — WAVE-PRIVATE
// producer-consumer: each wave stages ONLY its own A 64-row + B 64-row slices into its own
// 16 KiB LDS region (2-buf), so LDS data is wave-private and the K-loop has NO barriers.
// Per step: issue stage(k+1) [8 gl_lds] -> s_waitcnt vmcnt(8) [tile k's 8 loads retired,
// k+1's stay in flight] -> ds_read -> MFMA. r8's lockstep s_barrier (slowest-wave gate) gone.
// LDS 64 KiB -> 2 blocks/CU. Zero-conflict swizzle (proven r3/r5/r7/r8).
// Interleaved XCD mapping (proven r8: FETCH 335->58 MB): xcd=bid&7, colt fastest =>
// each A-panel read by exactly one XCD; dedup dead tail spreads uniformly mod 8.
__global__ __launch_bounds__(256, 2) void k_gemm(
    const u16* __restrict__ A, const u16* __restrict__ B,
    int M, int N, int K, int gx, const int* __restrict__ mrows,
    const float* __restrict__ rowscale, const float* __restrict__ bias,
    int relu, const float* __restrict__ residual,
    float* __restrict__ outF, u16* __restrict__ outH)
{
    __shared__ u16 lds[32768];   // 64 KiB: wave w owns u16[w*8192 .. +8192): [2buf][A 2048 | B 2048]
    int tid  = threadIdx.x;
    int lane = tid & 63, wid = tid >> 6;

    int xcd = blockIdx.x & 7;
    int i   = blockIdx.x >> 3;
    int colt = i % gx;
    int rowt = (i / gx) * 8 + xcd;
    int row0 = rowt * 128, col0 = colt * 128;
    if (mrows && row0 >= mrows[0] * SEQ) return;   // no barriers anywhere: trivially safe

    int wr = wid >> 1, wc = wid & 1;
    int m15 = lane & 15, g = lane >> 4;

    // staging: wave stages its own A slice rows [wr*64, wr*64+64) and B slice [wc*64, +64)
    // as 4 slots of 16 rows each; inverse-swizzled global source (row-in-slot q = lane>>2,
    // swizzle bits ((q>>1)&3) — identical for every slot since slot stride 16 rows).
    int q  = lane >> 2;
    int ce = ((lane & 3) * 8) ^ (((q >> 1) & 3) << 3);
    const u16* gA = A + (size_t)(row0 + wr * 64 + q) * K + ce;
    const u16* gB = B + (size_t)(col0 + wc * 64 + q) * K + ce;
    u16* myL = lds + wid * 8192;

    auto stage = [&](int buf, int kt) {
        int ko = kt * 32;
        #pragma unroll
        for (int j = 0; j < 4; ++j)
            gl16(gA + (size_t)(j * 16) * K + ko, myL + buf * 4096 + j * 512);
        #pragma unroll
        for (int j = 0; j < 4; ++j)
            gl16(gB + (size_t)(j * 16) * K + ko, myL + buf * 4096 + 2048 + j * 512);
    };

    f32x4 acc[4][4];
    #pragma unroll
    for (int m = 0; m < 4; ++m)
        #pragma unroll
        for (int n = 0; n < 4; ++n) { f32x4 z = {0.f,0.f,0.f,0.f}; acc[m][n] = z; }

    // swizzled k-offset (u16): region row r = m15 + m*16 -> (r>>1)&3 == (m15>>1)&3
    int ksw = (g * 8) ^ (((m15 >> 1) & 3) << 3);

    int NT = K / 32;
    stage(0, 0);                                  // 8 outstanding
    for (int kt = 0; kt < NT; ++kt) {
        if (kt + 1 < NT) {
            stage((kt + 1) & 1, kt + 1);          // 16 outstanding
            asm volatile("s_waitcnt vmcnt(8)" ::: "memory");   // tile k retired
        } else {
            asm volatile("s_waitcnt vmcnt(0)" ::: "memory");
        }
        __builtin_amdgcn_sched_barrier(0);
        const u16* ap = myL + (kt & 1) * 4096;
        bf16x8 af[4], bfr[4];
        #pragma unroll
        for (int m = 0; m < 4; ++m)
            af[m] = *(const bf16x8*)(ap + (m15 + m * 16) * 32 + ksw);
        #pragma unroll
        for (int n = 0; n < 4; ++n)
            bfr[n] = *(const bf16x8*)(ap + 2048 + (m15 + n * 16) * 32 + ksw);
        #pragma unroll
        for (int m = 0; m < 4; ++m)
            #pragma unroll
            for (int n = 0; n < 4; ++n)
                acc[m][n] = __builtin_amdgcn_mfma_f32_16x16x32_bf16(af[m], bfr[n], acc[m][n], 0, 0, 0);
    }

    // epilogue: C row = row0 + wr*64 + m*16 + g*4 + j ; col = col0 + wc*64 + n*16 + (lane&15)
    #pragma unroll
    for (int m = 0; m < 4; ++m) {
        int rbase = row0 + wr * 64 + m * 16 + g * 4;
        #pragma unroll
        for (int n = 0; n < 4; ++n) {
            int col = col0 + wc * 64 + n * 16 + m15;
            #pragma unroll
            for (int j = 0; j < 4; ++j) {
                int row = rbase + j;
                float v = acc[m][n][j];
                if (rowscale) v *= rowscale[row];
                if (bias)     v += bias[col];
                if (relu)     v = fmaxf(v, 0.f);
                if (residual) v += residual[(size_t)row * N + col];
                if (outF) outF[(size_t)row * N + col] = v;
                else      outH[(size_t)row * N + col] = f2b(v);
            }
        }
    }
}

// ---------------- per-node attention: online segment softmax + aggregate (RoPE eliminated:
// both sides rotated by the same position l -> orthogonal rotation cancels in the dot).
// Edge features indexed via compact fidx[e] (dedup'd fkv table). ------
__global__ __launch_bounds__(256, 2) void k_attn(
    const u16* __restrict__ qkv, const u16* __restrict__ ekv,
    const int* __restrict__ srcA, const int* __restrict__ fidx,
    const int* __restrict__ off, const int* __restrict__ elist,
    u16* __restrict__ agg)
{
    int n = blockIdx.x;
    int t = threadIdx.x;
    int pair = t >> 2, sub = t & 3;
    int l = pair >> 3, hd = pair & 7;
    int doff = hd * 64 + sub * 16;

    size_t qrow = ((size_t)n * SEQ + l) * 1536;
    float qi[16];
    {
        u16x8 qa = *(const u16x8*)&qkv[qrow + doff];
        u16x8 qb = *(const u16x8*)&qkv[qrow + doff + 8];
        #pragma unroll
        for (int i = 0; i < 8; ++i) { qi[i] = b2f(qa[i]); qi[i + 8] = b2f(qb[i]); }
    }

    float mrun = -INFINITY, s = 0.f;
    float av[16];
    #pragma unroll
    for (int i = 0; i < 16; ++i) av[i] = 0.f;

    int e0 = off[n], e1 = off[n + 1];
    for (int ii = e0; ii < e1; ++ii) {
        int e = elist[ii];
        int es = srcA[e];
        size_t krow = ((size_t)es * SEQ + l) * 1536 + 512;
        size_t erow = ((size_t)fidx[e] * SEQ + l) * 1024;

        u16x8 ka = *(const u16x8*)&qkv[krow + doff];
        u16x8 kb = *(const u16x8*)&qkv[krow + doff + 8];
        u16x8 ea = *(const u16x8*)&ekv[erow + doff];
        u16x8 eb = *(const u16x8*)&ekv[erow + doff + 8];

        float dot = 0.f;
        #pragma unroll
        for (int i = 0; i < 8; ++i) {
            dot += qi[i]     * (b2f(ka[i]) + b2f(ea[i]));
            dot += qi[i + 8] * (b2f(kb[i]) + b2f(eb[i]));
        }
        dot += __shfl_xor(dot, 1);
        dot += __shfl_xor(dot, 2);
        float alpha = dot * 0.125f;     // 1/sqrt(64)

        float mn = fmaxf(mrun, alpha);
        float f = expf(mrun - mn);      // mrun=-inf -> 0
        float p = expf(alpha - mn);
        s = s * f + p;

        u16x8 va  = *(const u16x8*)&qkv[krow + 512 + doff];
        u16x8 vb  = *(const u16x8*)&qkv[krow + 512 + doff + 8];
        u16x8 eva = *(const u16x8*)&ekv[erow + 512 + doff];
        u16x8 evb = *(const u16x8*)&ekv[erow + 512 + doff + 8];
        #pragma unroll
        for (int i = 0; i < 8; ++i) {
            av[i]     = av[i]     * f + p * (b2f(va[i]) + b2f(eva[i]));
            av[i + 8] = av[i + 8] * f + p * (b2f(vb[i]) + b2f(evb[i]));
        }
        mrun = mn;
    }

    float inv = 1.f / (s + 1e-16f);
    size_t orow = ((size_t)n * SEQ + l) * DIM + doff;
    #pragma unroll
    for (int i = 0; i < 16; ++i) agg[orow + i] = f2b(av[i] * inv);
}

extern "C" void kernel_launch(void* const* d_in, const int* in_sizes, int n_in,
                              void* d_out, int out_size, void* d_ws, size_t ws_size,
                              hipStream_t stream)
{
    const float* hidden = (const float*)d_in[0];
    const int*   eidx   = (const int*)d_in[1];
    const int*   srcA   = eidx;              // edge_index[0]
    const int*   dstA   = eidx + N_EDGES;    // edge_index[1]
    const int*   emap   = (const int*)d_in[2];
    const float* W_qkv  = (const float*)d_in[4];
    const float* W_e    = (const float*)d_in[5];
    const float* W_o    = (const float*)d_in[6];
    const float* xw     = (const float*)d_in[7];
    const float* xew    = (const float*)d_in[8];
    const float* pw     = (const float*)d_in[9];
    const float* W1     = (const float*)d_in[10];
    const float* b1     = (const float*)d_in[11];
    const float* W2     = (const float*)d_in[12];
    const float* b2     = (const float*)d_in[13];

    char* w = (char*)d_ws;
    auto alloc = [&](size_t bytes) { char* p = w; w += (bytes + 255) & ~(size_t)255; return p; };
    u16*  WtQKV  = (u16*)alloc((size_t)NLAYER * 1536 * 512 * 2);
    u16*  WtE    = (u16*)alloc((size_t)NLAYER * 1024 * 512 * 2);
    u16*  WtO    = (u16*)alloc((size_t)NLAYER * 512 * 512 * 2);
    u16*  Wt1    = (u16*)alloc((size_t)NLAYER * 1024 * 512 * 2);
    u16*  Wt2    = (u16*)alloc((size_t)NLAYER * 512 * 1024 * 2);
    float* s_x   = (float*)alloc((size_t)NROWS_X * 4);
    float* s_f   = (float*)alloc((size_t)NROWS_E * 4);
    float* s_post= (float*)alloc((size_t)NROWS_X * 4);
    int*  cnt    = (int*)alloc((N_NODES + 1) * 4);
    int*  off    = (int*)alloc((N_NODES + 1) * 4);
    int*  cur    = (int*)alloc(N_NODES * 4);
    int*  elist  = (int*)alloc(N_EDGES * 4);
    int*  flag   = (int*)alloc(N_EFEAT * 4);
    int*  newid  = (int*)alloc(N_EFEAT * 4);
    int*  ulist  = (int*)alloc(N_EFEAT * 4);
    int*  fidx   = (int*)alloc(N_EDGES * 4);
    int*  ucnt   = (int*)alloc(256);
    float* h_nodes = (float*)alloc((size_t)NROWS_X * DIM * 4);
    u16*  hn_bf  = (u16*)alloc((size_t)NROWS_X * DIM * 2);
    u16*  fbf    = (u16*)alloc((size_t)NROWS_E * DIM * 2);
    u16*  qkv    = (u16*)alloc((size_t)NROWS_X * 1536 * 2);
    u16*  aggB   = (u16*)alloc((size_t)NROWS_X * DIM * 2);
    float* out_buf = (float*)alloc((size_t)NROWS_X * DIM * 4);
    u16*  o_bf   = (u16*)alloc((size_t)NROWS_X * DIM * 2);
    u16*  ffmid  = (u16*)alloc((size_t)NROWS_X * 1024 * 2);
    // ekv scratch lives in d_out's edge region (exact size match: 131072*1024*2B = 16384*4096*4B)
    u16*  ekv    = (u16*)((float*)d_out + (size_t)NROWS_X * DIM);

    // ---- one-time prep (no initial h_nodes copy: layer 0 reads `hidden` directly) ----
    for (int l = 0; l < NLAYER; ++l) {
        k_tf<<<(512*1536 + 255)/256, 256, 0, stream>>>(W_qkv + (size_t)l*512*1536, WtQKV + (size_t)l*1536*512, xw  + l*512, 512, 1536);
        k_tf<<<(512*1024 + 255)/256, 256, 0, stream>>>(W_e   + (size_t)l*512*1024, WtE   + (size_t)l*1024*512, xew + l*512, 512, 1024);
        k_tf<<<(512*512  + 255)/256, 256, 0, stream>>>(W_o   + (size_t)l*512*512,  WtO   + (size_t)l*512*512,  nullptr,    512, 512);
        k_tf<<<(512*1024 + 255)/256, 256, 0, stream>>>(W1    + (size_t)l*512*1024, Wt1   + (size_t)l*1024*512, pw  + l*512, 512, 1024);
        k_tf<<<(1024*512 + 255)/256, 256, 0, stream>>>(W2    + (size_t)l*1024*512, Wt2   + (size_t)l*512*1024, nullptr,    1024, 512);
    }
    // dedup + compact-feature prep
    hipMemsetAsync(flag, 0, N_EFEAT * 4, stream);
    k_mark<<<N_EDGES/256, 256, 0, stream>>>(emap, flag);
    k_scanf<<<1, 256, 0, stream>>>(flag, newid, ulist, ucnt);
    k_fidx<<<N_EDGES/256, 256, 0, stream>>>(emap, newid, fidx);
    k_featprep<<<NROWS_E/4, 256, 0, stream>>>(hidden, ulist, ucnt, fbf, s_f);
    // CSR by dst
    hipMemsetAsync(cnt, 0, (N_NODES + 1) * 4, stream);
    hipMemsetAsync(cur, 0, N_NODES * 4, stream);
    k_count<<<N_EDGES/256, 256, 0, stream>>>(dstA, cnt);
    k_scan<<<1, 256, 0, stream>>>(cnt, off);
    k_fill<<<N_EDGES/256, 256, 0, stream>>>(dstA, off, cur, elist);

    // ---- layers ----
    for (int l = 0; l < NLAYER; ++l) {
        int last = (l == NLAYER - 1);
        const float* xsrc = (l == 0) ? hidden : h_nodes;   // layer-0 x = input nodes region
        k_rowprep<<<NROWS_X/4, 256, 0, stream>>>(xsrc, hn_bf, s_x);
        k_gemm<<<(NROWS_X/128)*(1536/128), 256, 0, stream>>>(hn_bf, WtQKV + (size_t)l*1536*512,
            NROWS_X, 1536, 512, 1536/128, nullptr, s_x, nullptr, 0, nullptr, nullptr, qkv);
        k_gemm<<<(NROWS_E/128)*(1024/128), 256, 0, stream>>>(fbf, WtE + (size_t)l*1024*512,
            NROWS_E, 1024, 512, 1024/128, ucnt, s_f, nullptr, 0, nullptr, nullptr, ekv);
        k_attn<<<N_NODES, 256, 0, stream>>>(qkv, ekv, srcA, fidx, off, elist, aggB);
        k_gemm<<<(NROWS_X/128)*(512/128), 256, 0, stream>>>(aggB, WtO + (size_t)l*512*512,
            NROWS_X, 512, 512, 512/128, nullptr, nullptr, nullptr, 0, xsrc, out_buf, nullptr);
        k_rowprep<<<NROWS_X/4, 256, 0, stream>>>(out_buf, o_bf, s_post);
        k_gemm<<<(NROWS_X/128)*(1024/128), 256, 0, stream>>>(o_bf, Wt1 + (size_t)l*1024*512,
            NROWS_X, 1024, 512, 1024/128, nullptr, s_post, b1 + l*1024, 1, nullptr, nullptr, ffmid);
        k_gemm<<<(NROWS_X/128)*(512/128), 256, 0, stream>>>(ffmid, Wt2 + (size_t)l*512*1024,
            NROWS_X, 512, 1024, 512/128, nullptr, nullptr, b2 + l*512, 0, out_buf,
            last ? (float*)d_out : h_nodes, nullptr);
    }

    // ---- edge-region copy (also overwrites ekv scratch; node region written by last FF2) ----
    hipMemcpyAsync((float*)d_out + (size_t)NROWS_X * DIM, hidden + (size_t)NROWS_X * DIM,
                   (size_t)N_EDGES * SEQ * DIM * 4, hipMemcpyDeviceToDevice, stream);
}

// Round 10
// 1538.197 us; speedup vs baseline: 1.2978x; 1.2978x over previous
//
#include <hip/hip_runtime.h>

typedef unsigned short u16;
typedef unsigned int   u32;
typedef u16   u16x8 __attribute__((ext_vector_type(8)));
typedef __bf16 bf16x8 __attribute__((ext_vector_type(8)));
typedef float f32x4 __attribute__((ext_vector_type(4)));
typedef float f32x4v __attribute__((ext_vector_type(4)));

#define N_NODES 4096
#define N_EDGES 16384
#define N_EFEAT 16384
#define SEQ 8
#define DIM 512
#define NLAYER 2
#define NROWS_X (N_NODES*SEQ)     /* 32768 */
#define NROWS_E (N_EDGES*SEQ)     /* 131072 */

__device__ __forceinline__ float b2f(u16 u){ return __uint_as_float(((u32)u)<<16); }
__device__ __forceinline__ u16 f2b(float f){ u32 b=__float_as_uint(f); b += 0x7FFFu + ((b>>16)&1u); return (u16)(b>>16); }

__device__ __forceinline__ void gl16(const u16* g, u16* l) {
    __builtin_amdgcn_global_load_lds((const __attribute__((address_space(1))) void*)g,
                                     (__attribute__((address_space(3))) void*)l, 16, 0, 0);
}

// ---------------- weight transpose + norm-w fold: dst[N][K] = src[K][N] * fold[K] ----------------
__global__ void k_tf(const float* __restrict__ src, u16* __restrict__ dst,
                     const float* __restrict__ fold, int K, int N)
{
    int idx = blockIdx.x * 256 + threadIdx.x;
    if (idx >= K * N) return;
    int c = idx / N, j = idx - c * N;
    float v = src[idx];
    if (fold) v *= fold[c];
    dst[(size_t)j * K + c] = f2b(v);
}

// ---------------- per-row: sumsq -> scale, write raw bf16 copy (wave per row) ----------------
__global__ void k_rowprep(const float* __restrict__ src, u16* __restrict__ dst,
                          float* __restrict__ scale)
{
    int row  = blockIdx.x * 4 + (threadIdx.x >> 6);
    int lane = threadIdx.x & 63;
    const float* p = src + (size_t)row * DIM;
    f32x4v v0 = *(const f32x4v*)(p + lane * 8);
    f32x4v v1 = *(const f32x4v*)(p + lane * 8 + 4);
    float ss = v0[0]*v0[0]+v0[1]*v0[1]+v0[2]*v0[2]+v0[3]*v0[3]
             + v1[0]*v1[0]+v1[1]*v1[1]+v1[2]*v1[2]+v1[3]*v1[3];
    #pragma unroll
    for (int d = 1; d < 64; d <<= 1) ss += __shfl_xor(ss, d);
    if (lane == 0) scale[row] = rsqrtf(ss / (float)DIM + 1e-6f);
    u16x8 o;
    #pragma unroll
    for (int i = 0; i < 4; ++i) o[i] = f2b(v0[i]);
    #pragma unroll
    for (int i = 0; i < 4; ++i) o[4+i] = f2b(v1[i]);
    *(u16x8*)(dst + (size_t)row * DIM + lane * 8) = o;
}

// ---------------- feature dedup: ekv[e] = (RMS(feat) @ We)[emap[e]] (RMS commutes w/ gather) --
__global__ void k_mark(const int* __restrict__ emap, int* __restrict__ flag)
{
    int e = blockIdx.x * 256 + threadIdx.x;
    if (e < N_EDGES) flag[emap[e]] = 1;
}
// single block: exclusive scan of flag[16384] -> newid; ulist[newid[m]] = m; ucnt = total
__global__ void k_scanf(const int* __restrict__ flag, int* __restrict__ newid,
                        int* __restrict__ ulist, int* __restrict__ ucnt)
{
    __shared__ int part[256];
    int t = threadIdx.x;
    int base = t * 64;
    int loc[64]; int s = 0;
    #pragma unroll
    for (int i = 0; i < 64; ++i) { loc[i] = s; s += flag[base + i]; }
    part[t] = s; __syncthreads();
    for (int d = 1; d < 256; d <<= 1) {
        int v = (t >= d) ? part[t - d] : 0;
        __syncthreads();
        part[t] += v;
        __syncthreads();
    }
    int pre = (t == 0) ? 0 : part[t - 1];
    #pragma unroll
    for (int i = 0; i < 64; ++i) {
        int m = base + i;
        int id = pre + loc[i];
        newid[m] = id;
        if (flag[m]) ulist[id] = m;
    }
    if (t == 255) ucnt[0] = part[255];
}
__global__ void k_fidx(const int* __restrict__ emap, const int* __restrict__ newid,
                       int* __restrict__ fidx)
{
    int e = blockIdx.x * 256 + threadIdx.x;
    if (e < N_EDGES) fidx[e] = newid[emap[e]];
}
// compact-feature rows: RMS scale + bf16 copy (wave per row); rows >= ucnt*8 skipped
__global__ void k_featprep(const float* __restrict__ hidden, const int* __restrict__ ulist,
                           const int* __restrict__ ucnt,
                           u16* __restrict__ fbf, float* __restrict__ scale)
{
    int fr = blockIdx.x * 4 + (threadIdx.x >> 6);   // compact row = j*8+l
    if (fr >= ucnt[0] * SEQ) return;
    int lane = threadIdx.x & 63;
    int j = fr >> 3, l = fr & 7;
    const float* p = hidden + ((size_t)(N_NODES + ulist[j]) * SEQ + l) * DIM;
    f32x4v v0 = *(const f32x4v*)(p + lane * 8);
    f32x4v v1 = *(const f32x4v*)(p + lane * 8 + 4);
    float ss = v0[0]*v0[0]+v0[1]*v0[1]+v0[2]*v0[2]+v0[3]*v0[3]
             + v1[0]*v1[0]+v1[1]*v1[1]+v1[2]*v1[2]+v1[3]*v1[3];
    #pragma unroll
    for (int d = 1; d < 64; d <<= 1) ss += __shfl_xor(ss, d);
    if (lane == 0) scale[fr] = rsqrtf(ss / (float)DIM + 1e-6f);
    u16x8 o;
    #pragma unroll
    for (int i = 0; i < 4; ++i) o[i] = f2b(v0[i]);
    #pragma unroll
    for (int i = 0; i < 4; ++i) o[4+i] = f2b(v1[i]);
    *(u16x8*)(fbf + (size_t)fr * DIM + lane * 8) = o;
}

// ---------------- CSR build ----------------
__global__ void k_count(const int* __restrict__ dstA, int* __restrict__ cnt)
{
    int e = blockIdx.x * 256 + threadIdx.x;
    if (e < N_EDGES) atomicAdd(&cnt[dstA[e]], 1);
}
__global__ void k_scan(const int* __restrict__ cnt, int* __restrict__ off)
{
    __shared__ int part[256];
    int t = threadIdx.x;
    int base = t * 16;
    int loc[16]; int s = 0;
    #pragma unroll
    for (int i = 0; i < 16; ++i) { loc[i] = s; s += cnt[base + i]; }
    part[t] = s; __syncthreads();
    for (int d = 1; d < 256; d <<= 1) {
        int v = (t >= d) ? part[t - d] : 0;
        __syncthreads();
        part[t] += v;
        __syncthreads();
    }
    int pre = (t == 0) ? 0 : part[t - 1];
    #pragma unroll
    for (int i = 0; i < 16; ++i) off[base + i] = pre + loc[i];
    if (t == 255) off[N_NODES] = part[255];
}
__global__ void k_fill(const int* __restrict__ dstA, const int* __restrict__ off,
                       int* __restrict__ cur, int* __restrict__ elist)
{
    int e = blockIdx.x * 256 + threadIdx.x;
    if (e < N_EDGES) {
        int d = dstA[e];
        int pos = off[d] + atomicAdd(&cur[d], 1);
        elist[pos] = e;
    }
}

// ---------------- bf16 MFMA GEMM: r7's proven best schedule (2-phase __syncthreads, 128x128,
// BK=32, 4 waves of 64x64, gl_lds w=16 dbuf, 32 KiB LDS, ~3.3 blocks/CU) combined with r8's
// proven interleaved XCD mapping (FETCH 335->58 MB): xcd=bid&7 (HW round-robin), colt fastest
// => each A row-panel is read by exactly ONE XCD (fetched once chip-wide, L2-resident);
// dedup dead tail spreads uniformly mod 8. Zero-conflict swizzle (proven r3..r9).
__global__ __launch_bounds__(256, 2) void k_gemm(
    const u16* __restrict__ A, const u16* __restrict__ B,
    int M, int N, int K, int gx, const int* __restrict__ mrows,
    const float* __restrict__ rowscale, const float* __restrict__ bias,
    int relu, const float* __restrict__ residual,
    float* __restrict__ outF, u16* __restrict__ outH)
{
    __shared__ u16 ldsA[2][128 * 32];
    __shared__ u16 ldsB[2][128 * 32];
    int tid  = threadIdx.x;
    int lane = tid & 63, wid = tid >> 6;

    // interleaved XCD mapping (requires rowtiles % 8 == 0 — true for all shapes here)
    int xcd  = blockIdx.x & 7;
    int i    = blockIdx.x >> 3;
    int colt = i % gx;
    int rowt = (i / gx) * 8 + xcd;
    int row0 = rowt * 128, col0 = colt * 128;
    if (mrows && row0 >= mrows[0] * SEQ) return;   // uniform exit, before any barrier

    // staging: wave w covers rows [w*32, w*32+32) in two 16-row slots; inverse-swizzled source
    int r0 = wid * 32 + (lane >> 2);
    int r1 = r0 + 16;
    int ce0 = ((lane & 3) * 8) ^ (((r0 >> 1) & 3) << 3);
    int ce1 = ((lane & 3) * 8) ^ (((r1 >> 1) & 3) << 3);
    const u16* ga0 = A + (size_t)(row0 + r0) * K + ce0;
    const u16* ga1 = A + (size_t)(row0 + r1) * K + ce1;
    const u16* gb0 = B + (size_t)(col0 + r0) * K + ce0;
    const u16* gb1 = B + (size_t)(col0 + r1) * K + ce1;

    auto stage = [&](int buf, int kt) {
        int ko = kt * 32;
        gl16(ga0 + ko, &ldsA[buf][wid * 1024]);
        gl16(ga1 + ko, &ldsA[buf][wid * 1024 + 512]);
        gl16(gb0 + ko, &ldsB[buf][wid * 1024]);
        gl16(gb1 + ko, &ldsB[buf][wid * 1024 + 512]);
    };

    f32x4 acc[4][4];
    #pragma unroll
    for (int m = 0; m < 4; ++m)
        #pragma unroll
        for (int n = 0; n < 4; ++n) { f32x4 z = {0.f,0.f,0.f,0.f}; acc[m][n] = z; }

    int wr = wid >> 1, wc = wid & 1;
    int m15 = lane & 15, g = lane >> 4;
    int arow_l = wr * 64 + m15;
    int brow_l = wc * 64 + m15;
    // swizzled k-offset (u16): row bits 1-2 come from m15 regardless of +m*16
    int ksw = (g * 8) ^ (((m15 >> 1) & 3) << 3);

    int NT = K / 32;
    stage(0, 0);
    int cur = 0;
    for (int kt = 0; kt < NT; ++kt) {
        __syncthreads();                        // drains vmcnt: buf[cur] ready, prev reads done
        if (kt + 1 < NT) stage(cur ^ 1, kt + 1);
        bf16x8 af[4], bfr[4];
        #pragma unroll
        for (int m = 0; m < 4; ++m)
            af[m] = *(const bf16x8*)&ldsA[cur][(arow_l + m * 16) * 32 + ksw];
        #pragma unroll
        for (int n = 0; n < 4; ++n)
            bfr[n] = *(const bf16x8*)&ldsB[cur][(brow_l + n * 16) * 32 + ksw];
        #pragma unroll
        for (int m = 0; m < 4; ++m)
            #pragma unroll
            for (int n = 0; n < 4; ++n)
                acc[m][n] = __builtin_amdgcn_mfma_f32_16x16x32_bf16(af[m], bfr[n], acc[m][n], 0, 0, 0);
        cur ^= 1;
    }

    // epilogue: C row = row0 + wr*64 + m*16 + g*4 + j ; col = col0 + wc*64 + n*16 + (lane&15)
    #pragma unroll
    for (int m = 0; m < 4; ++m) {
        int rbase = row0 + wr * 64 + m * 16 + g * 4;
        #pragma unroll
        for (int n = 0; n < 4; ++n) {
            int col = col0 + wc * 64 + n * 16 + m15;
            #pragma unroll
            for (int j = 0; j < 4; ++j) {
                int row = rbase + j;
                float v = acc[m][n][j];
                if (rowscale) v *= rowscale[row];
                if (bias)     v += bias[col];
                if (relu)     v = fmaxf(v, 0.f);
                if (residual) v += residual[(size_t)row * N + col];
                if (outF) outF[(size_t)row * N + col] = v;
                else      outH[(size_t)row * N + col] = f2b(v);
            }
        }
    }
}

// ---------------- per-node attention: online segment softmax + aggregate (RoPE eliminated:
// both sides rotated by the same position l -> orthogonal rotation cancels in the dot).
// Edge features indexed via compact fidx[e] (dedup'd fkv table). ------
__global__ __launch_bounds__(256, 2) void k_attn(
    const u16* __restrict__ qkv, const u16* __restrict__ ekv,
    const int* __restrict__ srcA, const int* __restrict__ fidx,
    const int* __restrict__ off, const int* __restrict__ elist,
    u16* __restrict__ agg)
{
    int n = blockIdx.x;
    int t = threadIdx.x;
    int pair = t >> 2, sub = t & 3;
    int l = pair >> 3, hd = pair & 7;
    int doff = hd * 64 + sub * 16;

    size_t qrow = ((size_t)n * SEQ + l) * 1536;
    float qi[16];
    {
        u16x8 qa = *(const u16x8*)&qkv[qrow + doff];
        u16x8 qb = *(const u16x8*)&qkv[qrow + doff + 8];
        #pragma unroll
        for (int i = 0; i < 8; ++i) { qi[i] = b2f(qa[i]); qi[i + 8] = b2f(qb[i]); }
    }

    float mrun = -INFINITY, s = 0.f;
    float av[16];
    #pragma unroll
    for (int i = 0; i < 16; ++i) av[i] = 0.f;

    int e0 = off[n], e1 = off[n + 1];
    for (int ii = e0; ii < e1; ++ii) {
        int e = elist[ii];
        int es = srcA[e];
        size_t krow = ((size_t)es * SEQ + l) * 1536 + 512;
        size_t erow = ((size_t)fidx[e] * SEQ + l) * 1024;

        u16x8 ka = *(const u16x8*)&qkv[krow + doff];
        u16x8 kb = *(const u16x8*)&qkv[krow + doff + 8];
        u16x8 ea = *(const u16x8*)&ekv[erow + doff];
        u16x8 eb = *(const u16x8*)&ekv[erow + doff + 8];

        float dot = 0.f;
        #pragma unroll
        for (int i = 0; i < 8; ++i) {
            dot += qi[i]     * (b2f(ka[i]) + b2f(ea[i]));
            dot += qi[i + 8] * (b2f(kb[i]) + b2f(eb[i]));
        }
        dot += __shfl_xor(dot, 1);
        dot += __shfl_xor(dot, 2);
        float alpha = dot * 0.125f;     // 1/sqrt(64)

        float mn = fmaxf(mrun, alpha);
        float f = expf(mrun - mn);      // mrun=-inf -> 0
        float p = expf(alpha - mn);
        s = s * f + p;

        u16x8 va  = *(const u16x8*)&qkv[krow + 512 + doff];
        u16x8 vb  = *(const u16x8*)&qkv[krow + 512 + doff + 8];
        u16x8 eva = *(const u16x8*)&ekv[erow + 512 + doff];
        u16x8 evb = *(const u16x8*)&ekv[erow + 512 + doff + 8];
        #pragma unroll
        for (int i = 0; i < 8; ++i) {
            av[i]     = av[i]     * f + p * (b2f(va[i]) + b2f(eva[i]));
            av[i + 8] = av[i + 8] * f + p * (b2f(vb[i]) + b2f(evb[i]));
        }
        mrun = mn;
    }

    float inv = 1.f / (s + 1e-16f);
    size_t orow = ((size_t)n * SEQ + l) * DIM + doff;
    #pragma unroll
    for (int i = 0; i < 16; ++i) agg[orow + i] = f2b(av[i] * inv);
}

extern "C" void kernel_launch(void* const* d_in, const int* in_sizes, int n_in,
                              void* d_out, int out_size, void* d_ws, size_t ws_size,
                              hipStream_t stream)
{
    const float* hidden = (const float*)d_in[0];
    const int*   eidx   = (const int*)d_in[1];
    const int*   srcA   = eidx;              // edge_index[0]
    const int*   dstA   = eidx + N_EDGES;    // edge_index[1]
    const int*   emap   = (const int*)d_in[2];
    const float* W_qkv  = (const float*)d_in[4];
    const float* W_e    = (const float*)d_in[5];
    const float* W_o    = (const float*)d_in[6];
    const float* xw     = (const float*)d_in[7];
    const float* xew    = (const float*)d_in[8];
    const float* pw     = (const float*)d_in[9];
    const float* W1     = (const float*)d_in[10];
    const float* b1     = (const float*)d_in[11];
    const float* W2     = (const float*)d_in[12];
    const float* b2     = (const float*)d_in[13];

    char* w = (char*)d_ws;
    auto alloc = [&](size_t bytes) { char* p = w; w += (bytes + 255) & ~(size_t)255; return p; };
    u16*  WtQKV  = (u16*)alloc((size_t)NLAYER * 1536 * 512 * 2);
    u16*  WtE    = (u16*)alloc((size_t)NLAYER * 1024 * 512 * 2);
    u16*  WtO    = (u16*)alloc((size_t)NLAYER * 512 * 512 * 2);
    u16*  Wt1    = (u16*)alloc((size_t)NLAYER * 1024 * 512 * 2);
    u16*  Wt2    = (u16*)alloc((size_t)NLAYER * 512 * 1024 * 2);
    float* s_x   = (float*)alloc((size_t)NROWS_X * 4);
    float* s_f   = (float*)alloc((size_t)NROWS_E * 4);
    float* s_post= (float*)alloc((size_t)NROWS_X * 4);
    int*  cnt    = (int*)alloc((N_NODES + 1) * 4);
    int*  off    = (int*)alloc((N_NODES + 1) * 4);
    int*  cur    = (int*)alloc(N_NODES * 4);
    int*  elist  = (int*)alloc(N_EDGES * 4);
    int*  flag   = (int*)alloc(N_EFEAT * 4);
    int*  newid  = (int*)alloc(N_EFEAT * 4);
    int*  ulist  = (int*)alloc(N_EFEAT * 4);
    int*  fidx   = (int*)alloc(N_EDGES * 4);
    int*  ucnt   = (int*)alloc(256);
    float* h_nodes = (float*)alloc((size_t)NROWS_X * DIM * 4);
    u16*  hn_bf  = (u16*)alloc((size_t)NROWS_X * DIM * 2);
    u16*  fbf    = (u16*)alloc((size_t)NROWS_E * DIM * 2);
    u16*  qkv    = (u16*)alloc((size_t)NROWS_X * 1536 * 2);
    u16*  aggB   = (u16*)alloc((size_t)NROWS_X * DIM * 2);
    float* out_buf = (float*)alloc((size_t)NROWS_X * DIM * 4);
    u16*  o_bf   = (u16*)alloc((size_t)NROWS_X * DIM * 2);
    u16*  ffmid  = (u16*)alloc((size_t)NROWS_X * 1024 * 2);
    // ekv scratch lives in d_out's edge region (exact size match: 131072*1024*2B = 16384*4096*4B)
    u16*  ekv    = (u16*)((float*)d_out + (size_t)NROWS_X * DIM);

    // ---- one-time prep (no initial h_nodes copy: layer 0 reads `hidden` directly) ----
    for (int l = 0; l < NLAYER; ++l) {
        k_tf<<<(512*1536 + 255)/256, 256, 0, stream>>>(W_qkv + (size_t)l*512*1536, WtQKV + (size_t)l*1536*512, xw  + l*512, 512, 1536);
        k_tf<<<(512*1024 + 255)/256, 256, 0, stream>>>(W_e   + (size_t)l*512*1024, WtE   + (size_t)l*1024*512, xew + l*512, 512, 1024);
        k_tf<<<(512*512  + 255)/256, 256, 0, stream>>>(W_o   + (size_t)l*512*512,  WtO   + (size_t)l*512*512,  nullptr,    512, 512);
        k_tf<<<(512*1024 + 255)/256, 256, 0, stream>>>(W1    + (size_t)l*512*1024, Wt1   + (size_t)l*1024*512, pw  + l*512, 512, 1024);
        k_tf<<<(1024*512 + 255)/256, 256, 0, stream>>>(W2    + (size_t)l*1024*512, Wt2   + (size_t)l*512*1024, nullptr,    1024, 512);
    }
    // dedup + compact-feature prep
    hipMemsetAsync(flag, 0, N_EFEAT * 4, stream);
    k_mark<<<N_EDGES/256, 256, 0, stream>>>(emap, flag);
    k_scanf<<<1, 256, 0, stream>>>(flag, newid, ulist, ucnt);
    k_fidx<<<N_EDGES/256, 256, 0, stream>>>(emap, newid, fidx);
    k_featprep<<<NROWS_E/4, 256, 0, stream>>>(hidden, ulist, ucnt, fbf, s_f);
    // CSR by dst
    hipMemsetAsync(cnt, 0, (N_NODES + 1) * 4, stream);
    hipMemsetAsync(cur, 0, N_NODES * 4, stream);
    k_count<<<N_EDGES/256, 256, 0, stream>>>(dstA, cnt);
    k_scan<<<1, 256, 0, stream>>>(cnt, off);
    k_fill<<<N_EDGES/256, 256, 0, stream>>>(dstA, off, cur, elist);

    // ---- layers ----
    for (int l = 0; l < NLAYER; ++l) {
        int last = (l == NLAYER - 1);
        const float* xsrc = (l == 0) ? hidden : h_nodes;   // layer-0 x = input nodes region
        k_rowprep<<<NROWS_X/4, 256, 0, stream>>>(xsrc, hn_bf, s_x);
        k_gemm<<<(NROWS_X/128)*(1536/128), 256, 0, stream>>>(hn_bf, WtQKV + (size_t)l*1536*512,
            NROWS_X, 1536, 512, 1536/128, nullptr, s_x, nullptr, 0, nullptr, nullptr, qkv);
        k_gemm<<<(NROWS_E/128)*(1024/128), 256, 0, stream>>>(fbf, WtE + (size_t)l*1024*512,
            NROWS_E, 1024, 512, 1024/128, ucnt, s_f, nullptr, 0, nullptr, nullptr, ekv);
        k_attn<<<N_NODES, 256, 0, stream>>>(qkv, ekv, srcA, fidx, off, elist, aggB);
        k_gemm<<<(NROWS_X/128)*(512/128), 256, 0, stream>>>(aggB, WtO + (size_t)l*512*512,
            NROWS_X, 512, 512, 512/128, nullptr, nullptr, nullptr, 0, xsrc, out_buf, nullptr);
        k_rowprep<<<NROWS_X/4, 256, 0, stream>>>(out_buf, o_bf, s_post);
        k_gemm<<<(NROWS_X/128)*(1024/128), 256, 0, stream>>>(o_bf, Wt1 + (size_t)l*1024*512,
            NROWS_X, 1024, 512, 1024/128, nullptr, s_post, b1 + l*1024, 1, nullptr, nullptr, ffmid);
        k_gemm<<<(NROWS_X/128)*(512/128), 256, 0, stream>>>(ffmid, Wt2 + (size_t)l*512*1024,
            NROWS_X, 512, 1024, 512/128, nullptr, nullptr, b2 + l*512, 0, out_buf,
            last ? (float*)d_out : h_nodes, nullptr);
    }

    // ---- edge-region copy (also overwrites ekv scratch; node region written by last FF2) ----
    hipMemcpyAsync((float*)d_out + (size_t)NROWS_X * DIM, hidden + (size_t)NROWS_X * DIM,
                   (size_t)N_EDGES * SEQ * DIM * 4, hipMemcpyDeviceToDevice, stream);
}

// Round 11
// 1342.343 us; speedup vs baseline: 1.4871x; 1.1459x over previous
//
#include <hip/hip_runtime.h>

typedef unsigned short u16;
typedef unsigned int   u32;
typedef u16   u16x8 __attribute__((ext_vector_type(8)));
typedef __bf16 bf16x8 __attribute__((ext_vector_type(8)));
typedef float f32x4 __attribute__((ext_vector_type(4)));
typedef float f32x4v __attribute__((ext_vector_type(4)));

#define N_NODES 4096
#define N_EDGES 16384
#define N_EFEAT 16384
#define SEQ 8
#define DIM 512
#define NLAYER 2
#define NROWS_X (N_NODES*SEQ)     /* 32768 */
#define NROWS_E (N_EDGES*SEQ)     /* 131072 */

__device__ __forceinline__ float b2f(u16 u){ return __uint_as_float(((u32)u)<<16); }
__device__ __forceinline__ u16 f2b(float f){ u32 b=__float_as_uint(f); b += 0x7FFFu + ((b>>16)&1u); return (u16)(b>>16); }

__device__ __forceinline__ void gl16(const u16* g, u16* l) {
    __builtin_amdgcn_global_load_lds((const __attribute__((address_space(1))) void*)g,
                                     (__attribute__((address_space(3))) void*)l, 16, 0, 0);
}

// ---------------- weight transpose + norm-w fold: dst[N][K] = src[K][N] * fold[K] ----------------
__global__ void k_tf(const float* __restrict__ src, u16* __restrict__ dst,
                     const float* __restrict__ fold, int K, int N)
{
    int idx = blockIdx.x * 256 + threadIdx.x;
    if (idx >= K * N) return;
    int c = idx / N, j = idx - c * N;
    float v = src[idx];
    if (fold) v *= fold[c];
    dst[(size_t)j * K + c] = f2b(v);
}

// ---------------- layer-0 row prep: bf16 copy + per-row SUMSQ (wave per row) ----------------
__global__ void k_rowprep(const float* __restrict__ src, u16* __restrict__ dst,
                          float* __restrict__ ssout)
{
    int row  = blockIdx.x * 4 + (threadIdx.x >> 6);
    int lane = threadIdx.x & 63;
    const float* p = src + (size_t)row * DIM;
    f32x4v v0 = *(const f32x4v*)(p + lane * 8);
    f32x4v v1 = *(const f32x4v*)(p + lane * 8 + 4);
    float ss = v0[0]*v0[0]+v0[1]*v0[1]+v0[2]*v0[2]+v0[3]*v0[3]
             + v1[0]*v1[0]+v1[1]*v1[1]+v1[2]*v1[2]+v1[3]*v1[3];
    #pragma unroll
    for (int d = 1; d < 64; d <<= 1) ss += __shfl_xor(ss, d);
    if (lane == 0) ssout[row] = ss;
    u16x8 o;
    #pragma unroll
    for (int i = 0; i < 4; ++i) o[i] = f2b(v0[i]);
    #pragma unroll
    for (int i = 0; i < 4; ++i) o[4+i] = f2b(v1[i]);
    *(u16x8*)(dst + (size_t)row * DIM + lane * 8) = o;
}

// ---------------- feature dedup: ekv[e] = (RMS(feat) @ We)[emap[e]] (RMS commutes w/ gather) --
__global__ void k_mark(const int* __restrict__ emap, int* __restrict__ flag)
{
    int e = blockIdx.x * 256 + threadIdx.x;
    if (e < N_EDGES) flag[emap[e]] = 1;
}
// single block: exclusive scan of flag[16384] -> newid; ulist[newid[m]] = m; ucnt = total
__global__ void k_scanf(const int* __restrict__ flag, int* __restrict__ newid,
                        int* __restrict__ ulist, int* __restrict__ ucnt)
{
    __shared__ int part[256];
    int t = threadIdx.x;
    int base = t * 64;
    int loc[64]; int s = 0;
    #pragma unroll
    for (int i = 0; i < 64; ++i) { loc[i] = s; s += flag[base + i]; }
    part[t] = s; __syncthreads();
    for (int d = 1; d < 256; d <<= 1) {
        int v = (t >= d) ? part[t - d] : 0;
        __syncthreads();
        part[t] += v;
        __syncthreads();
    }
    int pre = (t == 0) ? 0 : part[t - 1];
    #pragma unroll
    for (int i = 0; i < 64; ++i) {
        int m = base + i;
        int id = pre + loc[i];
        newid[m] = id;
        if (flag[m]) ulist[id] = m;
    }
    if (t == 255) ucnt[0] = part[255];
}
__global__ void k_fidx(const int* __restrict__ emap, const int* __restrict__ newid,
                       int* __restrict__ fidx)
{
    int e = blockIdx.x * 256 + threadIdx.x;
    if (e < N_EDGES) fidx[e] = newid[emap[e]];
}
// compact-feature rows: SUMSQ + bf16 copy (wave per row); rows >= ucnt*8 skipped
__global__ void k_featprep(const float* __restrict__ hidden, const int* __restrict__ ulist,
                           const int* __restrict__ ucnt,
                           u16* __restrict__ fbf, float* __restrict__ ssout)
{
    int fr = blockIdx.x * 4 + (threadIdx.x >> 6);   // compact row = j*8+l
    if (fr >= ucnt[0] * SEQ) return;
    int lane = threadIdx.x & 63;
    int j = fr >> 3, l = fr & 7;
    const float* p = hidden + ((size_t)(N_NODES + ulist[j]) * SEQ + l) * DIM;
    f32x4v v0 = *(const f32x4v*)(p + lane * 8);
    f32x4v v1 = *(const f32x4v*)(p + lane * 8 + 4);
    float ss = v0[0]*v0[0]+v0[1]*v0[1]+v0[2]*v0[2]+v0[3]*v0[3]
             + v1[0]*v1[0]+v1[1]*v1[1]+v1[2]*v1[2]+v1[3]*v1[3];
    #pragma unroll
    for (int d = 1; d < 64; d <<= 1) ss += __shfl_xor(ss, d);
    if (lane == 0) ssout[fr] = ss;
    u16x8 o;
    #pragma unroll
    for (int i = 0; i < 4; ++i) o[i] = f2b(v0[i]);
    #pragma unroll
    for (int i = 0; i < 4; ++i) o[4+i] = f2b(v1[i]);
    *(u16x8*)(fbf + (size_t)fr * DIM + lane * 8) = o;
}

// ---------------- CSR build ----------------
__global__ void k_count(const int* __restrict__ dstA, int* __restrict__ cnt)
{
    int e = blockIdx.x * 256 + threadIdx.x;
    if (e < N_EDGES) atomicAdd(&cnt[dstA[e]], 1);
}
__global__ void k_scan(const int* __restrict__ cnt, int* __restrict__ off)
{
    __shared__ int part[256];
    int t = threadIdx.x;
    int base = t * 16;
    int loc[16]; int s = 0;
    #pragma unroll
    for (int i = 0; i < 16; ++i) { loc[i] = s; s += cnt[base + i]; }
    part[t] = s; __syncthreads();
    for (int d = 1; d < 256; d <<= 1) {
        int v = (t >= d) ? part[t - d] : 0;
        __syncthreads();
        part[t] += v;
        __syncthreads();
    }
    int pre = (t == 0) ? 0 : part[t - 1];
    #pragma unroll
    for (int i = 0; i < 16; ++i) off[base + i] = pre + loc[i];
    if (t == 255) off[N_NODES] = part[255];
}
__global__ void k_fill(const int* __restrict__ dstA, const int* __restrict__ off,
                       int* __restrict__ cur, int* __restrict__ elist)
{
    int e = blockIdx.x * 256 + threadIdx.x;
    if (e < N_EDGES) {
        int d = dstA[e];
        int pos = off[d] + atomicAdd(&cur[d], 1);
        elist[pos] = e;
    }
}

// ---------------- bf16 MFMA GEMM: r10's proven config (2-phase __syncthreads, 128x128, BK=32,
// 4 waves of 64x64, gl_lds w=16 dbuf, 32 KiB LDS, interleaved-XCD mapping, 0-conflict swizzle).
// FUSED EPILOGUE: rowscale from raw sumsq (ssin: v *= rsqrt(ss/512+eps)), bias, relu,
// bf16 residual (resH), per-row output sumsq (ssout, shfl-reduced + atomicAdd), fp32/bf16 out.
__global__ __launch_bounds__(256, 2) void k_gemm(
    const u16* __restrict__ A, const u16* __restrict__ B,
    int M, int N, int K, int gx, const int* __restrict__ mrows,
    const float* __restrict__ ssin, const float* __restrict__ bias, int relu,
    const u16* __restrict__ resH, float* __restrict__ ssout,
    float* __restrict__ outF, u16* __restrict__ outH)
{
    __shared__ u16 ldsA[2][128 * 32];
    __shared__ u16 ldsB[2][128 * 32];
    int tid  = threadIdx.x;
    int lane = tid & 63, wid = tid >> 6;

    // interleaved XCD mapping (requires rowtiles % 8 == 0 — true for all shapes here)
    int xcd  = blockIdx.x & 7;
    int i    = blockIdx.x >> 3;
    int colt = i % gx;
    int rowt = (i / gx) * 8 + xcd;
    int row0 = rowt * 128, col0 = colt * 128;
    if (mrows && row0 >= mrows[0] * SEQ) return;   // uniform exit, before any barrier

    // staging: wave w covers rows [w*32, w*32+32) in two 16-row slots; inverse-swizzled source
    int r0 = wid * 32 + (lane >> 2);
    int r1 = r0 + 16;
    int ce0 = ((lane & 3) * 8) ^ (((r0 >> 1) & 3) << 3);
    int ce1 = ((lane & 3) * 8) ^ (((r1 >> 1) & 3) << 3);
    const u16* ga0 = A + (size_t)(row0 + r0) * K + ce0;
    const u16* ga1 = A + (size_t)(row0 + r1) * K + ce1;
    const u16* gb0 = B + (size_t)(col0 + r0) * K + ce0;
    const u16* gb1 = B + (size_t)(col0 + r1) * K + ce1;

    auto stage = [&](int buf, int kt) {
        int ko = kt * 32;
        gl16(ga0 + ko, &ldsA[buf][wid * 1024]);
        gl16(ga1 + ko, &ldsA[buf][wid * 1024 + 512]);
        gl16(gb0 + ko, &ldsB[buf][wid * 1024]);
        gl16(gb1 + ko, &ldsB[buf][wid * 1024 + 512]);
    };

    f32x4 acc[4][4];
    #pragma unroll
    for (int m = 0; m < 4; ++m)
        #pragma unroll
        for (int n = 0; n < 4; ++n) { f32x4 z = {0.f,0.f,0.f,0.f}; acc[m][n] = z; }

    int wr = wid >> 1, wc = wid & 1;
    int m15 = lane & 15, g = lane >> 4;
    int arow_l = wr * 64 + m15;
    int brow_l = wc * 64 + m15;
    // swizzled k-offset (u16): row bits 1-2 come from m15 regardless of +m*16
    int ksw = (g * 8) ^ (((m15 >> 1) & 3) << 3);

    int NT = K / 32;
    stage(0, 0);
    int cur = 0;
    for (int kt = 0; kt < NT; ++kt) {
        __syncthreads();                        // drains vmcnt: buf[cur] ready, prev reads done
        if (kt + 1 < NT) stage(cur ^ 1, kt + 1);
        bf16x8 af[4], bfr[4];
        #pragma unroll
        for (int m = 0; m < 4; ++m)
            af[m] = *(const bf16x8*)&ldsA[cur][(arow_l + m * 16) * 32 + ksw];
        #pragma unroll
        for (int n = 0; n < 4; ++n)
            bfr[n] = *(const bf16x8*)&ldsB[cur][(brow_l + n * 16) * 32 + ksw];
        #pragma unroll
        for (int m = 0; m < 4; ++m)
            #pragma unroll
            for (int n = 0; n < 4; ++n)
                acc[m][n] = __builtin_amdgcn_mfma_f32_16x16x32_bf16(af[m], bfr[n], acc[m][n], 0, 0, 0);
        cur ^= 1;
    }

    // fused epilogue: row = row0 + wr*64 + m*16 + g*4 + j ; col = col0 + wc*64 + n*16 + m15
    #pragma unroll
    for (int m = 0; m < 4; ++m) {
        #pragma unroll
        for (int j = 0; j < 4; ++j) {
            int row = row0 + wr * 64 + m * 16 + g * 4 + j;
            float sc = 0.f;
            if (ssin) sc = rsqrtf(ssin[row] * (1.f / (float)DIM) + 1e-6f);
            float ssa = 0.f;
            #pragma unroll
            for (int n = 0; n < 4; ++n) {
                int col = col0 + wc * 64 + n * 16 + m15;
                float v = acc[m][n][j];
                if (ssin) v *= sc;
                if (bias) v += bias[col];
                if (relu) v = fmaxf(v, 0.f);
                if (resH) v += b2f(resH[(size_t)row * N + col]);
                if (outF) outF[(size_t)row * N + col] = v;
                if (outH) outH[(size_t)row * N + col] = f2b(v);
                ssa += v * v;
            }
            if (ssout) {
                ssa += __shfl_xor(ssa, 1);
                ssa += __shfl_xor(ssa, 2);
                ssa += __shfl_xor(ssa, 4);
                ssa += __shfl_xor(ssa, 8);
                if (m15 == 0) atomicAdd(&ssout[row], ssa);
            }
        }
    }
}

// ---------------- per-node attention: online segment softmax + aggregate (RoPE eliminated:
// both sides rotated by the same position l -> orthogonal rotation cancels in the dot).
// Edge features indexed via compact fidx[e] (dedup'd fkv table). ------
__global__ __launch_bounds__(256, 2) void k_attn(
    const u16* __restrict__ qkv, const u16* __restrict__ ekv,
    const int* __restrict__ srcA, const int* __restrict__ fidx,
    const int* __restrict__ off, const int* __restrict__ elist,
    u16* __restrict__ agg)
{
    int n = blockIdx.x;
    int t = threadIdx.x;
    int pair = t >> 2, sub = t & 3;
    int l = pair >> 3, hd = pair & 7;
    int doff = hd * 64 + sub * 16;

    size_t qrow = ((size_t)n * SEQ + l) * 1536;
    float qi[16];
    {
        u16x8 qa = *(const u16x8*)&qkv[qrow + doff];
        u16x8 qb = *(const u16x8*)&qkv[qrow + doff + 8];
        #pragma unroll
        for (int i = 0; i < 8; ++i) { qi[i] = b2f(qa[i]); qi[i + 8] = b2f(qb[i]); }
    }

    float mrun = -INFINITY, s = 0.f;
    float av[16];
    #pragma unroll
    for (int i = 0; i < 16; ++i) av[i] = 0.f;

    int e0 = off[n], e1 = off[n + 1];
    for (int ii = e0; ii < e1; ++ii) {
        int e = elist[ii];
        int es = srcA[e];
        size_t krow = ((size_t)es * SEQ + l) * 1536 + 512;
        size_t erow = ((size_t)fidx[e] * SEQ + l) * 1024;

        u16x8 ka = *(const u16x8*)&qkv[krow + doff];
        u16x8 kb = *(const u16x8*)&qkv[krow + doff + 8];
        u16x8 ea = *(const u16x8*)&ekv[erow + doff];
        u16x8 eb = *(const u16x8*)&ekv[erow + doff + 8];

        float dot = 0.f;
        #pragma unroll
        for (int i = 0; i < 8; ++i) {
            dot += qi[i]     * (b2f(ka[i]) + b2f(ea[i]));
            dot += qi[i + 8] * (b2f(kb[i]) + b2f(eb[i]));
        }
        dot += __shfl_xor(dot, 1);
        dot += __shfl_xor(dot, 2);
        float alpha = dot * 0.125f;     // 1/sqrt(64)

        float mn = fmaxf(mrun, alpha);
        float f = expf(mrun - mn);      // mrun=-inf -> 0
        float p = expf(alpha - mn);
        s = s * f + p;

        u16x8 va  = *(const u16x8*)&qkv[krow + 512 + doff];
        u16x8 vb  = *(const u16x8*)&qkv[krow + 512 + doff + 8];
        u16x8 eva = *(const u16x8*)&ekv[erow + 512 + doff];
        u16x8 evb = *(const u16x8*)&ekv[erow + 512 + doff + 8];
        #pragma unroll
        for (int i = 0; i < 8; ++i) {
            av[i]     = av[i]     * f + p * (b2f(va[i]) + b2f(eva[i]));
            av[i + 8] = av[i + 8] * f + p * (b2f(vb[i]) + b2f(evb[i]));
        }
        mrun = mn;
    }

    float inv = 1.f / (s + 1e-16f);
    size_t orow = ((size_t)n * SEQ + l) * DIM + doff;
    #pragma unroll
    for (int i = 0; i < 16; ++i) agg[orow + i] = f2b(av[i] * inv);
}

extern "C" void kernel_launch(void* const* d_in, const int* in_sizes, int n_in,
                              void* d_out, int out_size, void* d_ws, size_t ws_size,
                              hipStream_t stream)
{
    const float* hidden = (const float*)d_in[0];
    const int*   eidx   = (const int*)d_in[1];
    const int*   srcA   = eidx;              // edge_index[0]
    const int*   dstA   = eidx + N_EDGES;    // edge_index[1]
    const int*   emap   = (const int*)d_in[2];
    const float* W_qkv  = (const float*)d_in[4];
    const float* W_e    = (const float*)d_in[5];
    const float* W_o    = (const float*)d_in[6];
    const float* xw     = (const float*)d_in[7];
    const float* xew    = (const float*)d_in[8];
    const float* pw     = (const float*)d_in[9];
    const float* W1     = (const float*)d_in[10];
    const float* b1     = (const float*)d_in[11];
    const float* W2     = (const float*)d_in[12];
    const float* b2     = (const float*)d_in[13];

    char* w = (char*)d_ws;
    auto alloc = [&](size_t bytes) { char* p = w; w += (bytes + 255) & ~(size_t)255; return p; };
    u16*  WtQKV  = (u16*)alloc((size_t)NLAYER * 1536 * 512 * 2);
    u16*  WtE    = (u16*)alloc((size_t)NLAYER * 1024 * 512 * 2);
    u16*  WtO    = (u16*)alloc((size_t)NLAYER * 512 * 512 * 2);
    u16*  Wt1    = (u16*)alloc((size_t)NLAYER * 1024 * 512 * 2);
    u16*  Wt2    = (u16*)alloc((size_t)NLAYER * 512 * 1024 * 2);
    float* ssx0  = (float*)alloc((size_t)NROWS_X * 4);
    float* ssx1  = (float*)alloc((size_t)NROWS_X * 4);
    float* ssp0  = (float*)alloc((size_t)NROWS_X * 4);
    float* ssp1  = (float*)alloc((size_t)NROWS_X * 4);
    float* s_f   = (float*)alloc((size_t)NROWS_E * 4);
    int*  cnt    = (int*)alloc((N_NODES + 1) * 4);
    int*  off    = (int*)alloc((N_NODES + 1) * 4);
    int*  cur    = (int*)alloc(N_NODES * 4);
    int*  elist  = (int*)alloc(N_EDGES * 4);
    int*  flag   = (int*)alloc(N_EFEAT * 4);
    int*  newid  = (int*)alloc(N_EFEAT * 4);
    int*  ulist  = (int*)alloc(N_EFEAT * 4);
    int*  fidx   = (int*)alloc(N_EDGES * 4);
    int*  ucnt   = (int*)alloc(256);
    u16*  hb     = (u16*)alloc((size_t)NROWS_X * DIM * 2);
    u16*  ob     = (u16*)alloc((size_t)NROWS_X * DIM * 2);
    u16*  fbf    = (u16*)alloc((size_t)NROWS_E * DIM * 2);
    u16*  qkv    = (u16*)alloc((size_t)NROWS_X * 1536 * 2);
    u16*  aggB   = (u16*)alloc((size_t)NROWS_X * DIM * 2);
    u16*  ffmid  = (u16*)alloc((size_t)NROWS_X * 1024 * 2);
    // ekv scratch lives in d_out's edge region (exact size match: 131072*1024*2B = 16384*4096*4B)
    u16*  ekv    = (u16*)((float*)d_out + (size_t)NROWS_X * DIM);
    float* ssx[2] = { ssx0, ssx1 };
    float* ssp[2] = { ssp0, ssp1 };

    // ---- one-time prep ----
    for (int l = 0; l < NLAYER; ++l) {
        k_tf<<<(512*1536 + 255)/256, 256, 0, stream>>>(W_qkv + (size_t)l*512*1536, WtQKV + (size_t)l*1536*512, xw  + l*512, 512, 1536);
        k_tf<<<(512*1024 + 255)/256, 256, 0, stream>>>(W_e   + (size_t)l*512*1024, WtE   + (size_t)l*1024*512, xew + l*512, 512, 1024);
        k_tf<<<(512*512  + 255)/256, 256, 0, stream>>>(W_o   + (size_t)l*512*512,  WtO   + (size_t)l*512*512,  nullptr,    512, 512);
        k_tf<<<(512*1024 + 255)/256, 256, 0, stream>>>(W1    + (size_t)l*512*1024, Wt1   + (size_t)l*1024*512, pw  + l*512, 512, 1024);
        k_tf<<<(1024*512 + 255)/256, 256, 0, stream>>>(W2    + (size_t)l*1024*512, Wt2   + (size_t)l*512*1024, nullptr,    1024, 512);
    }
    // zero atomic-sumsq accumulators (re-zeroed every call; graph-replay safe)
    hipMemsetAsync(ssx1, 0, NROWS_X * 4, stream);
    hipMemsetAsync(ssp0, 0, NROWS_X * 4, stream);
    hipMemsetAsync(ssp1, 0, NROWS_X * 4, stream);
    // dedup + compact-feature prep
    hipMemsetAsync(flag, 0, N_EFEAT * 4, stream);
    k_mark<<<N_EDGES/256, 256, 0, stream>>>(emap, flag);
    k_scanf<<<1, 256, 0, stream>>>(flag, newid, ulist, ucnt);
    k_fidx<<<N_EDGES/256, 256, 0, stream>>>(emap, newid, fidx);
    k_featprep<<<NROWS_E/4, 256, 0, stream>>>(hidden, ulist, ucnt, fbf, s_f);
    // CSR by dst
    hipMemsetAsync(cnt, 0, (N_NODES + 1) * 4, stream);
    hipMemsetAsync(cur, 0, N_NODES * 4, stream);
    k_count<<<N_EDGES/256, 256, 0, stream>>>(dstA, cnt);
    k_scan<<<1, 256, 0, stream>>>(cnt, off);
    k_fill<<<N_EDGES/256, 256, 0, stream>>>(dstA, off, cur, elist);
    // layer-0 node prep: bf16 copy + sumsq
    k_rowprep<<<NROWS_X/4, 256, 0, stream>>>(hidden, hb, ssx0);

    // ---- layers (all state bf16; RMS scales from fused sumsq) ----
    for (int l = 0; l < NLAYER; ++l) {
        int last = (l == NLAYER - 1);
        // qkv = rms(h)@Wqkv  (rowscale from ssx[l])
        k_gemm<<<(NROWS_X/128)*(1536/128), 256, 0, stream>>>(hb, WtQKV + (size_t)l*1536*512,
            NROWS_X, 1536, 512, 1536/128, nullptr,
            ssx[l], nullptr, 0, nullptr, nullptr, nullptr, qkv);
        // ekv = rms(feat)@We  (dedup'd rows; rowscale from s_f)
        k_gemm<<<(NROWS_E/128)*(1024/128), 256, 0, stream>>>(fbf, WtE + (size_t)l*1024*512,
            NROWS_E, 1024, 512, 1024/128, ucnt,
            s_f, nullptr, 0, nullptr, nullptr, nullptr, ekv);
        k_attn<<<N_NODES, 256, 0, stream>>>(qkv, ekv, srcA, fidx, off, elist, aggB);
        // out = h + agg@Wo   -> ob (bf16) + sumsq(out) -> ssp[l]
        k_gemm<<<(NROWS_X/128)*(512/128), 256, 0, stream>>>(aggB, WtO + (size_t)l*512*512,
            NROWS_X, 512, 512, 512/128, nullptr,
            nullptr, nullptr, 0, hb, ssp[l], nullptr, ob);
        // ffmid = relu(rms(out)@W1 + b1)   (rowscale from ssp[l])
        k_gemm<<<(NROWS_X/128)*(1024/128), 256, 0, stream>>>(ob, Wt1 + (size_t)l*1024*512,
            NROWS_X, 1024, 512, 1024/128, nullptr,
            ssp[l], b1 + l*1024, 1, nullptr, nullptr, nullptr, ffmid);
        // h' = out + ffmid@W2 + b2  -> hb (bf16) + sumsq -> ssx[l+1]; last: fp32 d_out
        k_gemm<<<(NROWS_X/128)*(512/128), 256, 0, stream>>>(ffmid, Wt2 + (size_t)l*512*1024,
            NROWS_X, 512, 1024, 512/128, nullptr,
            nullptr, b2 + l*512, 0, ob,
            last ? nullptr : ssx[1],
            last ? (float*)d_out : nullptr,
            last ? nullptr : hb);
    }

    // ---- edge-region copy (also overwrites ekv scratch; node region written by last FF2) ----
    hipMemcpyAsync((float*)d_out + (size_t)NROWS_X * DIM, hidden + (size_t)NROWS_X * DIM,
                   (size_t)N_EDGES * SEQ * DIM * 4, hipMemcpyDeviceToDevice, stream);
}

// Round 12
// 1341.520 us; speedup vs baseline: 1.4881x; 1.0006x over previous
//
#include <hip/hip_runtime.h>

typedef unsigned short u16;
typedef unsigned int   u32;
typedef u16   u16x8 __attribute__((ext_vector_type(8)));
typedef __bf16 bf16x8 __attribute__((ext_vector_type(8)));
typedef float f32x4 __attribute__((ext_vector_type(4)));
typedef float f32x4v __attribute__((ext_vector_type(4)));

#define N_NODES 4096
#define N_EDGES 16384
#define N_EFEAT 16384
#define SEQ 8
#define DIM 512
#define NLAYER 2
#define NROWS_X (N_NODES*SEQ)     /* 32768 */
#define NROWS_E (N_EDGES*SEQ)     /* 131072 */

__device__ __forceinline__ float b2f(u16 u){ return __uint_as_float(((u32)u)<<16); }
__device__ __forceinline__ u16 f2b(float f){ u32 b=__float_as_uint(f); b += 0x7FFFu + ((b>>16)&1u); return (u16)(b>>16); }

__device__ __forceinline__ void gl16(const u16* g, u16* l) {
    __builtin_amdgcn_global_load_lds((const __attribute__((address_space(1))) void*)g,
                                     (__attribute__((address_space(3))) void*)l, 16, 0, 0);
}

// ---------------- weight transpose + norm-w fold: dst[N][K] = src[K][N] * fold[K] ----------------
__global__ void k_tf(const float* __restrict__ src, u16* __restrict__ dst,
                     const float* __restrict__ fold, int K, int N)
{
    int idx = blockIdx.x * 256 + threadIdx.x;
    if (idx >= K * N) return;
    int c = idx / N, j = idx - c * N;
    float v = src[idx];
    if (fold) v *= fold[c];
    dst[(size_t)j * K + c] = f2b(v);
}

// ---------------- layer-0 row prep: bf16 copy + per-row SUMSQ (wave per row) ----------------
__global__ void k_rowprep(const float* __restrict__ src, u16* __restrict__ dst,
                          float* __restrict__ ssout)
{
    int row  = blockIdx.x * 4 + (threadIdx.x >> 6);
    int lane = threadIdx.x & 63;
    const float* p = src + (size_t)row * DIM;
    f32x4v v0 = *(const f32x4v*)(p + lane * 8);
    f32x4v v1 = *(const f32x4v*)(p + lane * 8 + 4);
    float ss = v0[0]*v0[0]+v0[1]*v0[1]+v0[2]*v0[2]+v0[3]*v0[3]
             + v1[0]*v1[0]+v1[1]*v1[1]+v1[2]*v1[2]+v1[3]*v1[3];
    #pragma unroll
    for (int d = 1; d < 64; d <<= 1) ss += __shfl_xor(ss, d);
    if (lane == 0) ssout[row] = ss;
    u16x8 o;
    #pragma unroll
    for (int i = 0; i < 4; ++i) o[i] = f2b(v0[i]);
    #pragma unroll
    for (int i = 0; i < 4; ++i) o[4+i] = f2b(v1[i]);
    *(u16x8*)(dst + (size_t)row * DIM + lane * 8) = o;
}

// ---------------- feature dedup: ekv[e] = (RMS(feat) @ We)[emap[e]] (RMS commutes w/ gather) --
__global__ void k_mark(const int* __restrict__ emap, int* __restrict__ flag)
{
    int e = blockIdx.x * 256 + threadIdx.x;
    if (e < N_EDGES) flag[emap[e]] = 1;
}
// single block: exclusive scan of flag[16384] -> newid; ulist[newid[m]] = m; ucnt = total
__global__ void k_scanf(const int* __restrict__ flag, int* __restrict__ newid,
                        int* __restrict__ ulist, int* __restrict__ ucnt)
{
    __shared__ int part[256];
    int t = threadIdx.x;
    int base = t * 64;
    int loc[64]; int s = 0;
    #pragma unroll
    for (int i = 0; i < 64; ++i) { loc[i] = s; s += flag[base + i]; }
    part[t] = s; __syncthreads();
    for (int d = 1; d < 256; d <<= 1) {
        int v = (t >= d) ? part[t - d] : 0;
        __syncthreads();
        part[t] += v;
        __syncthreads();
    }
    int pre = (t == 0) ? 0 : part[t - 1];
    #pragma unroll
    for (int i = 0; i < 64; ++i) {
        int m = base + i;
        int id = pre + loc[i];
        newid[m] = id;
        if (flag[m]) ulist[id] = m;
    }
    if (t == 255) ucnt[0] = part[255];
}
__global__ void k_fidx(const int* __restrict__ emap, const int* __restrict__ newid,
                       int* __restrict__ fidx)
{
    int e = blockIdx.x * 256 + threadIdx.x;
    if (e < N_EDGES) fidx[e] = newid[emap[e]];
}
// compact-feature rows: SUMSQ + bf16 copy (wave per row); rows >= ucnt*8 skipped
__global__ void k_featprep(const float* __restrict__ hidden, const int* __restrict__ ulist,
                           const int* __restrict__ ucnt,
                           u16* __restrict__ fbf, float* __restrict__ ssout)
{
    int fr = blockIdx.x * 4 + (threadIdx.x >> 6);   // compact row = j*8+l
    if (fr >= ucnt[0] * SEQ) return;
    int lane = threadIdx.x & 63;
    int j = fr >> 3, l = fr & 7;
    const float* p = hidden + ((size_t)(N_NODES + ulist[j]) * SEQ + l) * DIM;
    f32x4v v0 = *(const f32x4v*)(p + lane * 8);
    f32x4v v1 = *(const f32x4v*)(p + lane * 8 + 4);
    float ss = v0[0]*v0[0]+v0[1]*v0[1]+v0[2]*v0[2]+v0[3]*v0[3]
             + v1[0]*v1[0]+v1[1]*v1[1]+v1[2]*v1[2]+v1[3]*v1[3];
    #pragma unroll
    for (int d = 1; d < 64; d <<= 1) ss += __shfl_xor(ss, d);
    if (lane == 0) ssout[fr] = ss;
    u16x8 o;
    #pragma unroll
    for (int i = 0; i < 4; ++i) o[i] = f2b(v0[i]);
    #pragma unroll
    for (int i = 0; i < 4; ++i) o[4+i] = f2b(v1[i]);
    *(u16x8*)(fbf + (size_t)fr * DIM + lane * 8) = o;
}

// ---------------- CSR build ----------------
__global__ void k_count(const int* __restrict__ dstA, int* __restrict__ cnt)
{
    int e = blockIdx.x * 256 + threadIdx.x;
    if (e < N_EDGES) atomicAdd(&cnt[dstA[e]], 1);
}
__global__ void k_scan(const int* __restrict__ cnt, int* __restrict__ off)
{
    __shared__ int part[256];
    int t = threadIdx.x;
    int base = t * 16;
    int loc[16]; int s = 0;
    #pragma unroll
    for (int i = 0; i < 16; ++i) { loc[i] = s; s += cnt[base + i]; }
    part[t] = s; __syncthreads();
    for (int d = 1; d < 256; d <<= 1) {
        int v = (t >= d) ? part[t - d] : 0;
        __syncthreads();
        part[t] += v;
        __syncthreads();
    }
    int pre = (t == 0) ? 0 : part[t - 1];
    #pragma unroll
    for (int i = 0; i < 16; ++i) off[base + i] = pre + loc[i];
    if (t == 255) off[N_NODES] = part[255];
}
__global__ void k_fill(const int* __restrict__ dstA, const int* __restrict__ off,
                       int* __restrict__ cur, int* __restrict__ elist)
{
    int e = blockIdx.x * 256 + threadIdx.x;
    if (e < N_EDGES) {
        int d = dstA[e];
        int pos = off[d] + atomicAdd(&cur[d], 1);
        elist[pos] = e;
    }
}

// ---------------- bf16 MFMA GEMM: r10/r11's proven config (2-phase __syncthreads, 128x128,
// BK=32, 4 waves of 64x64, gl_lds w=16 dbuf, 32 KiB LDS, interleaved-XCD, 0-conflict swizzle,
// fused epilogue). SINGLE CHANGE r11->r12: __launch_bounds__(256,4) — 4 blocks/CU (was ~3.3).
// Budget: 56 arch VGPR + 64 acc AGPR = 120 <= 128 cap; LDS 4x32 = 128 <= 160 KiB.
// Spill guard: if WRITE_SIZE balloons (r4 signature), revert to (256,2).
__global__ __launch_bounds__(256, 4) void k_gemm(
    const u16* __restrict__ A, const u16* __restrict__ B,
    int M, int N, int K, int gx, const int* __restrict__ mrows,
    const float* __restrict__ ssin, const float* __restrict__ bias, int relu,
    const u16* __restrict__ resH, float* __restrict__ ssout,
    float* __restrict__ outF, u16* __restrict__ outH)
{
    __shared__ u16 ldsA[2][128 * 32];
    __shared__ u16 ldsB[2][128 * 32];
    int tid  = threadIdx.x;
    int lane = tid & 63, wid = tid >> 6;

    // interleaved XCD mapping (requires rowtiles % 8 == 0 — true for all shapes here)
    int xcd  = blockIdx.x & 7;
    int i    = blockIdx.x >> 3;
    int colt = i % gx;
    int rowt = (i / gx) * 8 + xcd;
    int row0 = rowt * 128, col0 = colt * 128;
    if (mrows && row0 >= mrows[0] * SEQ) return;   // uniform exit, before any barrier

    // staging: wave w covers rows [w*32, w*32+32) in two 16-row slots; inverse-swizzled source
    int r0 = wid * 32 + (lane >> 2);
    int r1 = r0 + 16;
    int ce0 = ((lane & 3) * 8) ^ (((r0 >> 1) & 3) << 3);
    int ce1 = ((lane & 3) * 8) ^ (((r1 >> 1) & 3) << 3);
    const u16* ga0 = A + (size_t)(row0 + r0) * K + ce0;
    const u16* ga1 = A + (size_t)(row0 + r1) * K + ce1;
    const u16* gb0 = B + (size_t)(col0 + r0) * K + ce0;
    const u16* gb1 = B + (size_t)(col0 + r1) * K + ce1;

    auto stage = [&](int buf, int kt) {
        int ko = kt * 32;
        gl16(ga0 + ko, &ldsA[buf][wid * 1024]);
        gl16(ga1 + ko, &ldsA[buf][wid * 1024 + 512]);
        gl16(gb0 + ko, &ldsB[buf][wid * 1024]);
        gl16(gb1 + ko, &ldsB[buf][wid * 1024 + 512]);
    };

    f32x4 acc[4][4];
    #pragma unroll
    for (int m = 0; m < 4; ++m)
        #pragma unroll
        for (int n = 0; n < 4; ++n) { f32x4 z = {0.f,0.f,0.f,0.f}; acc[m][n] = z; }

    int wr = wid >> 1, wc = wid & 1;
    int m15 = lane & 15, g = lane >> 4;
    int arow_l = wr * 64 + m15;
    int brow_l = wc * 64 + m15;
    // swizzled k-offset (u16): row bits 1-2 come from m15 regardless of +m*16
    int ksw = (g * 8) ^ (((m15 >> 1) & 3) << 3);

    int NT = K / 32;
    stage(0, 0);
    int cur = 0;
    for (int kt = 0; kt < NT; ++kt) {
        __syncthreads();                        // drains vmcnt: buf[cur] ready, prev reads done
        if (kt + 1 < NT) stage(cur ^ 1, kt + 1);
        bf16x8 af[4], bfr[4];
        #pragma unroll
        for (int m = 0; m < 4; ++m)
            af[m] = *(const bf16x8*)&ldsA[cur][(arow_l + m * 16) * 32 + ksw];
        #pragma unroll
        for (int n = 0; n < 4; ++n)
            bfr[n] = *(const bf16x8*)&ldsB[cur][(brow_l + n * 16) * 32 + ksw];
        #pragma unroll
        for (int m = 0; m < 4; ++m)
            #pragma unroll
            for (int n = 0; n < 4; ++n)
                acc[m][n] = __builtin_amdgcn_mfma_f32_16x16x32_bf16(af[m], bfr[n], acc[m][n], 0, 0, 0);
        cur ^= 1;
    }

    // fused epilogue: row = row0 + wr*64 + m*16 + g*4 + j ; col = col0 + wc*64 + n*16 + m15
    #pragma unroll
    for (int m = 0; m < 4; ++m) {
        #pragma unroll
        for (int j = 0; j < 4; ++j) {
            int row = row0 + wr * 64 + m * 16 + g * 4 + j;
            float sc = 0.f;
            if (ssin) sc = rsqrtf(ssin[row] * (1.f / (float)DIM) + 1e-6f);
            float ssa = 0.f;
            #pragma unroll
            for (int n = 0; n < 4; ++n) {
                int col = col0 + wc * 64 + n * 16 + m15;
                float v = acc[m][n][j];
                if (ssin) v *= sc;
                if (bias) v += bias[col];
                if (relu) v = fmaxf(v, 0.f);
                if (resH) v += b2f(resH[(size_t)row * N + col]);
                if (outF) outF[(size_t)row * N + col] = v;
                if (outH) outH[(size_t)row * N + col] = f2b(v);
                ssa += v * v;
            }
            if (ssout) {
                ssa += __shfl_xor(ssa, 1);
                ssa += __shfl_xor(ssa, 2);
                ssa += __shfl_xor(ssa, 4);
                ssa += __shfl_xor(ssa, 8);
                if (m15 == 0) atomicAdd(&ssout[row], ssa);
            }
        }
    }
}

// ---------------- per-node attention: online segment softmax + aggregate (RoPE eliminated:
// both sides rotated by the same position l -> orthogonal rotation cancels in the dot).
// Edge features indexed via compact fidx[e] (dedup'd fkv table). ------
__global__ __launch_bounds__(256, 2) void k_attn(
    const u16* __restrict__ qkv, const u16* __restrict__ ekv,
    const int* __restrict__ srcA, const int* __restrict__ fidx,
    const int* __restrict__ off, const int* __restrict__ elist,
    u16* __restrict__ agg)
{
    int n = blockIdx.x;
    int t = threadIdx.x;
    int pair = t >> 2, sub = t & 3;
    int l = pair >> 3, hd = pair & 7;
    int doff = hd * 64 + sub * 16;

    size_t qrow = ((size_t)n * SEQ + l) * 1536;
    float qi[16];
    {
        u16x8 qa = *(const u16x8*)&qkv[qrow + doff];
        u16x8 qb = *(const u16x8*)&qkv[qrow + doff + 8];
        #pragma unroll
        for (int i = 0; i < 8; ++i) { qi[i] = b2f(qa[i]); qi[i + 8] = b2f(qb[i]); }
    }

    float mrun = -INFINITY, s = 0.f;
    float av[16];
    #pragma unroll
    for (int i = 0; i < 16; ++i) av[i] = 0.f;

    int e0 = off[n], e1 = off[n + 1];
    for (int ii = e0; ii < e1; ++ii) {
        int e = elist[ii];
        int es = srcA[e];
        size_t krow = ((size_t)es * SEQ + l) * 1536 + 512;
        size_t erow = ((size_t)fidx[e] * SEQ + l) * 1024;

        u16x8 ka = *(const u16x8*)&qkv[krow + doff];
        u16x8 kb = *(const u16x8*)&qkv[krow + doff + 8];
        u16x8 ea = *(const u16x8*)&ekv[erow + doff];
        u16x8 eb = *(const u16x8*)&ekv[erow + doff + 8];

        float dot = 0.f;
        #pragma unroll
        for (int i = 0; i < 8; ++i) {
            dot += qi[i]     * (b2f(ka[i]) + b2f(ea[i]));
            dot += qi[i + 8] * (b2f(kb[i]) + b2f(eb[i]));
        }
        dot += __shfl_xor(dot, 1);
        dot += __shfl_xor(dot, 2);
        float alpha = dot * 0.125f;     // 1/sqrt(64)

        float mn = fmaxf(mrun, alpha);
        float f = expf(mrun - mn);      // mrun=-inf -> 0
        float p = expf(alpha - mn);
        s = s * f + p;

        u16x8 va  = *(const u16x8*)&qkv[krow + 512 + doff];
        u16x8 vb  = *(const u16x8*)&qkv[krow + 512 + doff + 8];
        u16x8 eva = *(const u16x8*)&ekv[erow + 512 + doff];
        u16x8 evb = *(const u16x8*)&ekv[erow + 512 + doff + 8];
        #pragma unroll
        for (int i = 0; i < 8; ++i) {
            av[i]     = av[i]     * f + p * (b2f(va[i]) + b2f(eva[i]));
            av[i + 8] = av[i + 8] * f + p * (b2f(vb[i]) + b2f(evb[i]));
        }
        mrun = mn;
    }

    float inv = 1.f / (s + 1e-16f);
    size_t orow = ((size_t)n * SEQ + l) * DIM + doff;
    #pragma unroll
    for (int i = 0; i < 16; ++i) agg[orow + i] = f2b(av[i] * inv);
}

extern "C" void kernel_launch(void* const* d_in, const int* in_sizes, int n_in,
                              void* d_out, int out_size, void* d_ws, size_t ws_size,
                              hipStream_t stream)
{
    const float* hidden = (const float*)d_in[0];
    const int*   eidx   = (const int*)d_in[1];
    const int*   srcA   = eidx;              // edge_index[0]
    const int*   dstA   = eidx + N_EDGES;    // edge_index[1]
    const int*   emap   = (const int*)d_in[2];
    const float* W_qkv  = (const float*)d_in[4];
    const float* W_e    = (const float*)d_in[5];
    const float* W_o    = (const float*)d_in[6];
    const float* xw     = (const float*)d_in[7];
    const float* xew    = (const float*)d_in[8];
    const float* pw     = (const float*)d_in[9];
    const float* W1     = (const float*)d_in[10];
    const float* b1     = (const float*)d_in[11];
    const float* W2     = (const float*)d_in[12];
    const float* b2     = (const float*)d_in[13];

    char* w = (char*)d_ws;
    auto alloc = [&](size_t bytes) { char* p = w; w += (bytes + 255) & ~(size_t)255; return p; };
    u16*  WtQKV  = (u16*)alloc((size_t)NLAYER * 1536 * 512 * 2);
    u16*  WtE    = (u16*)alloc((size_t)NLAYER * 1024 * 512 * 2);
    u16*  WtO    = (u16*)alloc((size_t)NLAYER * 512 * 512 * 2);
    u16*  Wt1    = (u16*)alloc((size_t)NLAYER * 1024 * 512 * 2);
    u16*  Wt2    = (u16*)alloc((size_t)NLAYER * 512 * 1024 * 2);
    float* ssx0  = (float*)alloc((size_t)NROWS_X * 4);
    float* ssx1  = (float*)alloc((size_t)NROWS_X * 4);
    float* ssp0  = (float*)alloc((size_t)NROWS_X * 4);
    float* ssp1  = (float*)alloc((size_t)NROWS_X * 4);
    float* s_f   = (float*)alloc((size_t)NROWS_E * 4);
    int*  cnt    = (int*)alloc((N_NODES + 1) * 4);
    int*  off    = (int*)alloc((N_NODES + 1) * 4);
    int*  cur    = (int*)alloc(N_NODES * 4);
    int*  elist  = (int*)alloc(N_EDGES * 4);
    int*  flag   = (int*)alloc(N_EFEAT * 4);
    int*  newid  = (int*)alloc(N_EFEAT * 4);
    int*  ulist  = (int*)alloc(N_EFEAT * 4);
    int*  fidx   = (int*)alloc(N_EDGES * 4);
    int*  ucnt   = (int*)alloc(256);
    u16*  hb     = (u16*)alloc((size_t)NROWS_X * DIM * 2);
    u16*  ob     = (u16*)alloc((size_t)NROWS_X * DIM * 2);
    u16*  fbf    = (u16*)alloc((size_t)NROWS_E * DIM * 2);
    u16*  qkv    = (u16*)alloc((size_t)NROWS_X * 1536 * 2);
    u16*  aggB   = (u16*)alloc((size_t)NROWS_X * DIM * 2);
    u16*  ffmid  = (u16*)alloc((size_t)NROWS_X * 1024 * 2);
    // ekv scratch lives in d_out's edge region (exact size match: 131072*1024*2B = 16384*4096*4B)
    u16*  ekv    = (u16*)((float*)d_out + (size_t)NROWS_X * DIM);
    float* ssx[2] = { ssx0, ssx1 };
    float* ssp[2] = { ssp0, ssp1 };

    // ---- one-time prep ----
    for (int l = 0; l < NLAYER; ++l) {
        k_tf<<<(512*1536 + 255)/256, 256, 0, stream>>>(W_qkv + (size_t)l*512*1536, WtQKV + (size_t)l*1536*512, xw  + l*512, 512, 1536);
        k_tf<<<(512*1024 + 255)/256, 256, 0, stream>>>(W_e   + (size_t)l*512*1024, WtE   + (size_t)l*1024*512, xew + l*512, 512, 1024);
        k_tf<<<(512*512  + 255)/256, 256, 0, stream>>>(W_o   + (size_t)l*512*512,  WtO   + (size_t)l*512*512,  nullptr,    512, 512);
        k_tf<<<(512*1024 + 255)/256, 256, 0, stream>>>(W1    + (size_t)l*512*1024, Wt1   + (size_t)l*1024*512, pw  + l*512, 512, 1024);
        k_tf<<<(1024*512 + 255)/256, 256, 0, stream>>>(W2    + (size_t)l*1024*512, Wt2   + (size_t)l*512*1024, nullptr,    1024, 512);
    }
    // zero atomic-sumsq accumulators (re-zeroed every call; graph-replay safe)
    hipMemsetAsync(ssx1, 0, NROWS_X * 4, stream);
    hipMemsetAsync(ssp0, 0, NROWS_X * 4, stream);
    hipMemsetAsync(ssp1, 0, NROWS_X * 4, stream);
    // dedup + compact-feature prep
    hipMemsetAsync(flag, 0, N_EFEAT * 4, stream);
    k_mark<<<N_EDGES/256, 256, 0, stream>>>(emap, flag);
    k_scanf<<<1, 256, 0, stream>>>(flag, newid, ulist, ucnt);
    k_fidx<<<N_EDGES/256, 256, 0, stream>>>(emap, newid, fidx);
    k_featprep<<<NROWS_E/4, 256, 0, stream>>>(hidden, ulist, ucnt, fbf, s_f);
    // CSR by dst
    hipMemsetAsync(cnt, 0, (N_NODES + 1) * 4, stream);
    hipMemsetAsync(cur, 0, N_NODES * 4, stream);
    k_count<<<N_EDGES/256, 256, 0, stream>>>(dstA, cnt);
    k_scan<<<1, 256, 0, stream>>>(cnt, off);
    k_fill<<<N_EDGES/256, 256, 0, stream>>>(dstA, off, cur, elist);
    // layer-0 node prep: bf16 copy + sumsq
    k_rowprep<<<NROWS_X/4, 256, 0, stream>>>(hidden, hb, ssx0);

    // ---- layers (all state bf16; RMS scales from fused sumsq) ----
    for (int l = 0; l < NLAYER; ++l) {
        int last = (l == NLAYER - 1);
        // qkv = rms(h)@Wqkv  (rowscale from ssx[l])
        k_gemm<<<(NROWS_X/128)*(1536/128), 256, 0, stream>>>(hb, WtQKV + (size_t)l*1536*512,
            NROWS_X, 1536, 512, 1536/128, nullptr,
            ssx[l], nullptr, 0, nullptr, nullptr, nullptr, qkv);
        // ekv = rms(feat)@We  (dedup'd rows; rowscale from s_f)
        k_gemm<<<(NROWS_E/128)*(1024/128), 256, 0, stream>>>(fbf, WtE + (size_t)l*1024*512,
            NROWS_E, 1024, 512, 1024/128, ucnt,
            s_f, nullptr, 0, nullptr, nullptr, nullptr, ekv);
        k_attn<<<N_NODES, 256, 0, stream>>>(qkv, ekv, srcA, fidx, off, elist, aggB);
        // out = h + agg@Wo   -> ob (bf16) + sumsq(out) -> ssp[l]
        k_gemm<<<(NROWS_X/128)*(512/128), 256, 0, stream>>>(aggB, WtO + (size_t)l*512*512,
            NROWS_X, 512, 512, 512/128, nullptr,
            nullptr, nullptr, 0, hb, ssp[l], nullptr, ob);
        // ffmid = relu(rms(out)@W1 + b1)   (rowscale from ssp[l])
        k_gemm<<<(NROWS_X/128)*(1024/128), 256, 0, stream>>>(ob, Wt1 + (size_t)l*1024*512,
            NROWS_X, 1024, 512, 1024/128, nullptr,
            ssp[l], b1 + l*1024, 1, nullptr, nullptr, nullptr, ffmid);
        // h' = out + ffmid@W2 + b2  -> hb (bf16) + sumsq -> ssx[l+1]; last: fp32 d_out
        k_gemm<<<(NROWS_X/128)*(512/128), 256, 0, stream>>>(ffmid, Wt2 + (size_t)l*512*1024,
            NROWS_X, 512, 1024, 512/128, nullptr,
            nullptr, b2 + l*512, 0, ob,
            last ? nullptr : ssx[1],
            last ? (float*)d_out : nullptr,
            last ? nullptr : hb);
    }

    // ---- edge-region copy (also overwrites ekv scratch; node region written by last FF2) ----
    hipMemcpyAsync((float*)d_out + (size_t)NROWS_X * DIM, hidden + (size_t)NROWS_X * DIM,
                   (size_t)N_EDGES * SEQ * DIM * 4, hipMemcpyDeviceToDevice, stream);
}